// Round 1
// baseline (166.087 us; speedup 1.0000x reference)
//
#include <hip/hip_runtime.h>
#include <hip/hip_fp16.h>

// Problem constants (B,S,H,N_IN,N_PROC,R) = (4,1024,1024,64,16,128)
#define T_TOK 4096   // B*S tokens
#define H_DIM 1024
#define NIN   64
#define NP    16
#define R_DIM 128
#define S_DIM 1024
#define N1    (NP * R_DIM)   // 2048 = concat low-rank dim

typedef _Float16 half8  __attribute__((ext_vector_type(8)));
typedef _Float16 half4v __attribute__((ext_vector_type(4)));
typedef float    floatx4 __attribute__((ext_vector_type(4)));

typedef __attribute__((address_space(3))) unsigned char lds_u8_t;
typedef __attribute__((address_space(1))) unsigned char gbl_u8_t;

// async global->LDS, 16B per lane; LDS dest is wave-uniform base + lane*16
__device__ __forceinline__ void g2l16(const void* g, void* l) {
  __builtin_amdgcn_global_load_lds((const gbl_u8_t*)g, (lds_u8_t*)l, 16, 0, 0);
}

// ---------------- gates: conv(k=5 over S, full mix over 64 ch) + sigmoid ----
// grid = T/16 blocks, 256 thr = 16 tokens x 16 procs
__global__ __launch_bounds__(256)
void gates_kernel(const float* __restrict__ enr, const float* __restrict__ cw,
                  const float* __restrict__ cb, float* __restrict__ gates) {
  __shared__ float sw[NP][321];   // [n][dh*64+j], row stride 321 breaks bank aliasing
  __shared__ float se[20][NIN];   // 16 tokens + 2-halo each side
  const int tid = threadIdx.x;
  const int t0 = blockIdx.x * 16;
  const int b  = t0 / S_DIM;
  const int s0 = t0 % S_DIM;      // 16 | S so a block never straddles b
  for (int i = tid; i < NP * 320; i += 256) sw[i / 320][i % 320] = cw[i];
  for (int i = tid; i < 20 * NIN; i += 256) {
    int r = i >> 6, c = i & 63;
    int s = s0 + r - 2;
    se[r][c] = (s >= 0 && s < S_DIM) ? enr[((size_t)b * S_DIM + s) * NIN + c] : 0.f;
  }
  __syncthreads();
  const int lt = tid >> 4, n = tid & 15;
  float acc = cb[n];
  #pragma unroll
  for (int dh = 0; dh < 5; ++dh) {
    const float* wrow = &sw[n][dh * 64];
    const float* erow = se[lt + dh];
    #pragma unroll
    for (int j = 0; j < NIN; ++j) acc += erow[j] * wrow[j];
  }
  gates[(size_t)(t0 + lt) * NP + n] = 1.f / (1.f + expf(-acc));
}

// ---------------- fp32 -> fp16 cast, float4 vectorized ----------------------
__global__ __launch_bounds__(256)
void cast_f2h(const float* __restrict__ src, _Float16* __restrict__ dst, int n4) {
  int i = blockIdx.x * 256 + threadIdx.x;
  if (i >= n4) return;
  float4 v = reinterpret_cast<const float4*>(src)[i];
  half4v o;
  o[0] = (_Float16)v.x; o[1] = (_Float16)v.y; o[2] = (_Float16)v.z; o[3] = (_Float16)v.w;
  reinterpret_cast<half4v*>(dst)[i] = o;
}

// ---------------- tiled transpose + cast (rows x cols -> cols x rows) -------
__global__ __launch_bounds__(256)
void transpose_cast(const float* __restrict__ src, _Float16* __restrict__ dst,
                    int rows, int cols, long sblk, long dblk) {
  src += (size_t)blockIdx.z * sblk;
  dst += (size_t)blockIdx.z * dblk;
  __shared__ float tile[32][33];
  const int c0 = blockIdx.x * 32, r0 = blockIdx.y * 32;
  const int tx = threadIdx.x & 31, ty = threadIdx.x >> 5;  // 32 x 8
  #pragma unroll
  for (int k = 0; k < 32; k += 8)
    tile[ty + k][tx] = src[(size_t)(r0 + ty + k) * cols + c0 + tx];
  __syncthreads();
  #pragma unroll
  for (int k = 0; k < 32; k += 8)
    dst[(size_t)(c0 + ty + k) * rows + r0 + tx] = (_Float16)tile[tx][ty + k];
}

// ---------------- MFMA GEMM: C(MxN) = A(MxK) * BT(NxK)^T --------------------
// BM x 128 tile, BK=32, 4 waves in 2x2, 16x16x32 f16 MFMA, m97-style 2-barrier
// K-loop with global_load_lds width-16 staging. GATE: C = fp16(acc * gate[row][bn])
template <int BM, int GATE>
__global__ __launch_bounds__(256)
void gemm_bt(const _Float16* __restrict__ A, const _Float16* __restrict__ BT,
             const float* __restrict__ gates, void* __restrict__ Cv,
             const int N, const int K) {
  constexpr int BN = 128;
  constexpr int WM = BM / 2;       // per-wave M extent (2x2 wave grid)
  constexpr int WN = BN / 2;
  constexpr int MI = WM / 16;
  constexpr int NJ = WN / 16;
  constexpr int CA = BM / 64;      // A stage calls per wave (1024B each)
  constexpr int CB = BN / 64;
  __shared__ _Float16 sA[BM * 32]; // [m][k] row-major, 64B rows
  __shared__ _Float16 sB[BN * 32]; // [n][k] row-major

  const int tid  = threadIdx.x;
  const int wave = tid >> 6, lane = tid & 63;
  const int m0 = blockIdx.y * BM, n0 = blockIdx.x * BN;
  const int wr = (wave >> 1) * WM, wc = (wave & 1) * WN;
  const int sub = lane >> 2;            // staging: row within 16-row chunk
  const int kc  = (lane & 3) * 8;       // staging: k offset (8 halves = 16B)
  const int fr = lane & 15, quad = lane >> 4;

  const _Float16* gA = A  + (size_t)(m0 + (wave * CA) * 16 + sub) * K + kc;
  const _Float16* gB = BT + (size_t)(n0 + (wave * CB) * 16 + sub) * K + kc;
  _Float16* lA = sA + (wave * CA) * 512;  // 512 halves = 1024B per call
  _Float16* lB = sB + (wave * CB) * 512;

  floatx4 acc[MI][NJ];
  #pragma unroll
  for (int i = 0; i < MI; ++i)
    #pragma unroll
    for (int j = 0; j < NJ; ++j) acc[i][j] = (floatx4)0.f;

  for (int k0 = 0; k0 < K; k0 += 32) {
    __syncthreads();                       // LDS free before overwrite
    #pragma unroll
    for (int c = 0; c < CA; ++c) g2l16(gA + (size_t)c * 16 * K + k0, lA + c * 512);
    #pragma unroll
    for (int c = 0; c < CB; ++c) g2l16(gB + (size_t)c * 16 * K + k0, lB + c * 512);
    __syncthreads();                       // drains vmcnt before barrier
    half8 af[MI], bfr[NJ];
    #pragma unroll
    for (int i = 0; i < MI; ++i)
      af[i] = *reinterpret_cast<const half8*>(&sA[(wr + i * 16 + fr) * 32 + quad * 8]);
    #pragma unroll
    for (int j = 0; j < NJ; ++j)
      bfr[j] = *reinterpret_cast<const half8*>(&sB[(wc + j * 16 + fr) * 32 + quad * 8]);
    #pragma unroll
    for (int i = 0; i < MI; ++i)
      #pragma unroll
      for (int j = 0; j < NJ; ++j)
        acc[i][j] = __builtin_amdgcn_mfma_f32_16x16x32_f16(af[i], bfr[j], acc[i][j], 0, 0, 0);
  }

  // C/D layout: col = lane&15, row = quad*4 + reg  (guide §3, m89-verified)
  if (GATE) {
    _Float16* C = (_Float16*)Cv;   // bn == blockIdx.x since BN==128
    #pragma unroll
    for (int i = 0; i < MI; ++i) {
      #pragma unroll
      for (int r = 0; r < 4; ++r) {
        const int row = m0 + wr + i * 16 + quad * 4 + r;
        const float g = gates[row * NP + blockIdx.x];
        #pragma unroll
        for (int j = 0; j < NJ; ++j) {
          const int col = n0 + wc + j * 16 + fr;
          C[(size_t)row * N + col] = (_Float16)(acc[i][j][r] * g);
        }
      }
    }
  } else {
    float* C = (float*)Cv;
    #pragma unroll
    for (int i = 0; i < MI; ++i)
      #pragma unroll
      for (int r = 0; r < 4; ++r) {
        const int row = m0 + wr + i * 16 + quad * 4 + r;
        #pragma unroll
        for (int j = 0; j < NJ; ++j) {
          const int col = n0 + wc + j * 16 + fr;
          C[(size_t)row * N + col] = acc[i][j][r];
        }
      }
  }
}

extern "C" void kernel_launch(void* const* d_in, const int* in_sizes, int n_in,
                              void* d_out, int out_size, void* d_ws, size_t ws_size,
                              hipStream_t stream) {
  const float* inter = (const float*)d_in[0];  // (B,S,H)
  const float* enr   = (const float*)d_in[1];  // (B,S,64)
  const float* convw = (const float*)d_in[2];  // (16,1,5,64)
  const float* convb = (const float*)d_in[3];  // (16,)
  const float* dproj = (const float*)d_in[4];  // (16,1024,128)
  const float* uproj = (const float*)d_in[5];  // (16,128,1024)
  float* out   = (float*)d_out;                    // (B,S,H) fp32
  float* gates = out + (size_t)T_TOK * H_DIM;      // (B,S,16) fp32, output 1

  // workspace: Xh(8MB) | BT1(4MB) | UT(4MB) | Dsc(16MB)  -> 32MB total
  _Float16* Xh  = (_Float16*)d_ws;
  _Float16* BT1 = Xh  + (size_t)T_TOK * H_DIM;   // down^T: (2048 x 1024) N-major
  _Float16* UT  = BT1 + (size_t)N1 * H_DIM;      // up^T:   (1024 x 2048)
  _Float16* Dsc = UT  + (size_t)H_DIM * N1;      // gated down: (4096 x 2048) fp16

  // 1. gates (fp32 exact), straight into d_out tail; GEMM1 reads them back
  gates_kernel<<<T_TOK / 16, 256, 0, stream>>>(enr, convw, convb, gates);
  // 2. X -> fp16
  cast_f2h<<<(T_TOK * H_DIM / 4) / 256, 256, 0, stream>>>(inter, Xh, T_TOK * H_DIM / 4);
  // 3. down_proj[n] (1024x128) -> BT1 block n (128x1024): B^T operand for GEMM1
  transpose_cast<<<dim3(R_DIM / 32, H_DIM / 32, NP), 256, 0, stream>>>(
      dproj, BT1, H_DIM, R_DIM, (long)H_DIM * R_DIM, (long)H_DIM * R_DIM);
  // 4. up_proj (2048x1024) -> UT (1024x2048): B^T operand for GEMM2
  transpose_cast<<<dim3(H_DIM / 32, N1 / 32, 1), 256, 0, stream>>>(
      uproj, UT, N1, H_DIM, 0, 0);
  // 5. Dsc[t, n*128+r] = gate[t,n] * sum_h X[t,h] * down_proj[n,h,r]
  gemm_bt<128, 1><<<dim3(N1 / 128, T_TOK / 128), 256, 0, stream>>>(
      Xh, BT1, gates, (void*)Dsc, N1, H_DIM);
  // 6. out[t,h] = sum_nr Dsc[t,nr] * up_proj[nr,h]   (BM=64 -> 512 blocks, 2/CU)
  gemm_bt<64, 0><<<dim3(H_DIM / 128, T_TOK / 64), 256, 0, stream>>>(
      Dsc, UT, nullptr, (void*)out, H_DIM, N1);
}

// Round 2
// 146.358 us; speedup vs baseline: 1.1348x; 1.1348x over previous
//
#include <hip/hip_runtime.h>
#include <hip/hip_fp16.h>

// Problem constants (B,S,H,N_IN,N_PROC,R) = (4,1024,1024,64,16,128)
#define T_TOK 4096   // B*S tokens
#define H_DIM 1024
#define NIN   64
#define NP    16
#define R_DIM 128
#define S_DIM 1024
#define N1    (NP * R_DIM)   // 2048

typedef _Float16 half8  __attribute__((ext_vector_type(8)));
typedef _Float16 half4v __attribute__((ext_vector_type(4)));
typedef float    floatx4 __attribute__((ext_vector_type(4)));

typedef __attribute__((address_space(3))) unsigned char lds_u8_t;
typedef __attribute__((address_space(1))) unsigned char gbl_u8_t;

// async global->LDS, 16B/lane; HW writes lane i at ldsbase + i*16 (wave-uniform base)
__device__ __forceinline__ void g2l16(const void* g, void* l) {
  __builtin_amdgcn_global_load_lds((const gbl_u8_t*)g, (lds_u8_t*)l, 16, 0, 0);
}

// ---------------- fused prep: gates + cast + 2 transposes in ONE dispatch ---
// block ranges: [0,256) gates | [256,4352) castX | [4352,6400) dprojT | [6400,8448) uprojT
#define GATES_NB 256
#define CAST_NB  4096
#define DT_NB    2048
#define UT_NB    2048
#define PREP_NB  (GATES_NB + CAST_NB + DT_NB + UT_NB)

__global__ __launch_bounds__(256)
void prep_kernel(const float* __restrict__ enr, const float* __restrict__ cw,
                 const float* __restrict__ cb, const float* __restrict__ inter,
                 const float* __restrict__ dproj, const float* __restrict__ uproj,
                 float* __restrict__ gates, _Float16* __restrict__ Xh,
                 _Float16* __restrict__ BT1, _Float16* __restrict__ UT) {
  __shared__ __align__(16) char smem_raw[25664];
  const int tid = threadIdx.x;
  int bx = blockIdx.x;

  if (bx < GATES_NB) {   // ---- gates: conv(k=5, 64ch mix) + sigmoid ----
    float (*sw)[321] = (float (*)[321])smem_raw;            // 16*321*4 = 20544 B
    float (*se)[NIN] = (float (*)[NIN])(smem_raw + 20544);  // 20*64*4  =  5120 B
    const int t0 = bx * 16;
    const int b = t0 / S_DIM, s0 = t0 % S_DIM;   // 16 | S: no b-straddle
    for (int i = tid; i < NP * 320; i += 256) sw[i / 320][i % 320] = cw[i];
    for (int i = tid; i < 20 * NIN; i += 256) {
      int r = i >> 6, c = i & 63, s = s0 + r - 2;
      se[r][c] = (s >= 0 && s < S_DIM) ? enr[((size_t)b * S_DIM + s) * NIN + c] : 0.f;
    }
    __syncthreads();
    const int lt = tid >> 4, n = tid & 15;
    float acc = cb[n];
    #pragma unroll
    for (int dh = 0; dh < 5; ++dh) {
      const float* wrow = &sw[n][dh * 64];
      const float* erow = se[lt + dh];
      #pragma unroll
      for (int j = 0; j < NIN; ++j) acc += erow[j] * wrow[j];
    }
    gates[(size_t)(t0 + lt) * NP + n] = 1.f / (1.f + expf(-acc));
    return;
  }
  bx -= GATES_NB;
  if (bx < CAST_NB) {    // ---- X fp32 -> fp16, float4 vectorized ----
    int i = bx * 256 + tid;
    float4 v = reinterpret_cast<const float4*>(inter)[i];
    half4v o;
    o[0] = (_Float16)v.x; o[1] = (_Float16)v.y; o[2] = (_Float16)v.z; o[3] = (_Float16)v.w;
    reinterpret_cast<half4v*>(Xh)[i] = o;
    return;
  }
  bx -= CAST_NB;
  // ---- tiled transpose+cast ----
  const float* src; _Float16* dst; int rows, cols, bxt, byt;
  if (bx < DT_NB) {      // dproj[n]: (1024x128) -> BT1 block n (128x1024)
    int n = bx >> 7, rem = bx & 127;
    src = dproj + (size_t)n * H_DIM * R_DIM;
    dst = BT1 + (size_t)n * R_DIM * H_DIM;
    rows = H_DIM; cols = R_DIM; bxt = rem & 3; byt = rem >> 2;
  } else {               // uproj: (2048x1024) -> UT (1024x2048)
    bx -= DT_NB;
    src = uproj; dst = UT; rows = N1; cols = H_DIM;
    bxt = bx & 31; byt = bx >> 5;
  }
  float (*tile)[33] = (float (*)[33])smem_raw;
  const int c0 = bxt * 32, r0 = byt * 32;
  const int tx = tid & 31, ty = tid >> 5;   // 32 x 8
  #pragma unroll
  for (int k = 0; k < 32; k += 8)
    tile[ty + k][tx] = src[(size_t)(r0 + ty + k) * cols + c0 + tx];
  __syncthreads();
  #pragma unroll
  for (int k = 0; k < 32; k += 8)
    dst[(size_t)(c0 + ty + k) * rows + r0 + tx] = (_Float16)tile[tx][ty + k];
}

// ---------------- MFMA GEMM: C(MxN) = A(MxK) * BT(NxK)^T --------------------
// BM x 128 tile, BK=64 (128B LDS rows), 2x2 waves, 16x16x32 f16 MFMA.
// XOR-swizzled LDS: lane (r=lane>>3, s=lane&7) of each 1KB g2l16 call fetches
// global chunk q = s ^ r, so read slot for (row,chunk q) is q ^ (row&7):
// 16 read lanes -> 8 four-bank groups x 2 = 2-way = conflict-free (m136).
template <int BM, int GATE>
__global__ __launch_bounds__(256)
void gemm_bt(const _Float16* __restrict__ A, const _Float16* __restrict__ BT,
             const float* __restrict__ gates, void* __restrict__ Cv,
             const int N, const int K) {
  constexpr int BN = 128, BK = 64;
  constexpr int WM = BM / 2, WN = BN / 2;
  constexpr int MI = WM / 16, NJ = WN / 16;
  constexpr int CA = BM / 32, CB = BN / 32;   // 1KB staging calls per wave
  __shared__ _Float16 sA[BM * BK];   // [m][k] 128B rows, chunk-swizzled
  __shared__ _Float16 sB[BN * BK];

  const int tid = threadIdx.x, wave = tid >> 6, lane = tid & 63;
  const int m0 = blockIdx.y * BM, n0 = blockIdx.x * BN;
  const int wr = (wave >> 1) * WM, wc = (wave & 1) * WN;
  const int rl = lane >> 3;          // row within 8-row call
  const int q  = (lane & 7) ^ rl;    // swizzle: global chunk this lane fetches
  const int fr = lane & 15, quad = lane >> 4;

  const _Float16* gA = A  + (size_t)(m0 + wave * CA * 8 + rl) * K + q * 8;
  const _Float16* gB = BT + (size_t)(n0 + wave * CB * 8 + rl) * K + q * 8;
  _Float16* lA = sA + wave * CA * 512;
  _Float16* lB = sB + wave * CB * 512;

  floatx4 acc[MI][NJ];
  #pragma unroll
  for (int i = 0; i < MI; ++i)
    #pragma unroll
    for (int j = 0; j < NJ; ++j) acc[i][j] = (floatx4)0.f;

  for (int k0 = 0; k0 < K; k0 += BK) {
    __syncthreads();
    #pragma unroll
    for (int c = 0; c < CA; ++c) g2l16(gA + (size_t)c * 8 * K + k0, lA + c * 512);
    #pragma unroll
    for (int c = 0; c < CB; ++c) g2l16(gB + (size_t)c * 8 * K + k0, lB + c * 512);
    __syncthreads();
    #pragma unroll
    for (int h = 0; h < 2; ++h) {            // two k-halves of the 64-K tile
      const int sa = ((quad + 4 * h) ^ (fr & 7)) * 8;  // swizzled slot offset
      half8 af[MI], bf[NJ];
      #pragma unroll
      for (int i = 0; i < MI; ++i)
        af[i] = *reinterpret_cast<const half8*>(&sA[(wr + i * 16 + fr) * 64 + sa]);
      #pragma unroll
      for (int j = 0; j < NJ; ++j)
        bf[j] = *reinterpret_cast<const half8*>(&sB[(wc + j * 16 + fr) * 64 + sa]);
      #pragma unroll
      for (int i = 0; i < MI; ++i)
        #pragma unroll
        for (int j = 0; j < NJ; ++j)
          acc[i][j] = __builtin_amdgcn_mfma_f32_16x16x32_f16(af[i], bf[j], acc[i][j], 0, 0, 0);
    }
  }

  // C/D layout: col = lane&15, row = quad*4 + reg (m89-verified)
  if (GATE) {
    _Float16* C = (_Float16*)Cv;   // BN==128 -> blockIdx.x == neuron n
    #pragma unroll
    for (int i = 0; i < MI; ++i)
      #pragma unroll
      for (int r = 0; r < 4; ++r) {
        const int row = m0 + wr + i * 16 + quad * 4 + r;
        const float g = gates[row * NP + blockIdx.x];
        #pragma unroll
        for (int j = 0; j < NJ; ++j)
          C[(size_t)row * N + n0 + wc + j * 16 + fr] = (_Float16)(acc[i][j][r] * g);
      }
  } else {
    float* C = (float*)Cv;
    #pragma unroll
    for (int i = 0; i < MI; ++i)
      #pragma unroll
      for (int r = 0; r < 4; ++r) {
        const int row = m0 + wr + i * 16 + quad * 4 + r;
        #pragma unroll
        for (int j = 0; j < NJ; ++j)
          C[(size_t)row * N + n0 + wc + j * 16 + fr] = acc[i][j][r];
      }
  }
}

extern "C" void kernel_launch(void* const* d_in, const int* in_sizes, int n_in,
                              void* d_out, int out_size, void* d_ws, size_t ws_size,
                              hipStream_t stream) {
  const float* inter = (const float*)d_in[0];  // (B,S,H)
  const float* enr   = (const float*)d_in[1];  // (B,S,64)
  const float* convw = (const float*)d_in[2];  // (16,1,5,64)
  const float* convb = (const float*)d_in[3];  // (16,)
  const float* dproj = (const float*)d_in[4];  // (16,1024,128)
  const float* uproj = (const float*)d_in[5];  // (16,128,1024)
  float* out   = (float*)d_out;                // (B,S,H) fp32
  float* gates = out + (size_t)T_TOK * H_DIM;  // (B,S,16) fp32 = output 1

  // workspace: Xh(8MB) | BT1(4MB) | UT(4MB) | Dsc(16MB)
  _Float16* Xh  = (_Float16*)d_ws;
  _Float16* BT1 = Xh  + (size_t)T_TOK * H_DIM;
  _Float16* UT  = BT1 + (size_t)N1 * H_DIM;
  _Float16* Dsc = UT  + (size_t)H_DIM * N1;

  // 1. all prep in one dispatch
  prep_kernel<<<PREP_NB, 256, 0, stream>>>(enr, convw, convb, inter, dproj, uproj,
                                           gates, Xh, BT1, UT);
  // 2. Dsc[t, n*128+r] = gate[t,n] * sum_h X[t,h] * dproj[n,h,r]
  gemm_bt<128, 1><<<dim3(N1 / 128, T_TOK / 128), 256, 0, stream>>>(
      Xh, BT1, gates, (void*)Dsc, N1, H_DIM);
  // 3. out[t,h] = sum_nr Dsc[t,nr] * uproj[nr,h]   (BM=64 -> 512 blocks)
  gemm_bt<64, 0><<<dim3(H_DIM / 128, T_TOK / 64), 256, 0, stream>>>(
      Dsc, UT, nullptr, (void*)out, H_DIM, N1);
}

// Round 3
// 139.839 us; speedup vs baseline: 1.1877x; 1.0466x over previous
//
#include <hip/hip_runtime.h>
#include <hip/hip_fp16.h>

// Problem constants (B,S,H,N_IN,N_PROC,R) = (4,1024,1024,64,16,128)
#define T_TOK 4096   // B*S tokens
#define H_DIM 1024
#define NIN   64
#define NP    16
#define R_DIM 128
#define S_DIM 1024
#define N1    (NP * R_DIM)   // 2048

typedef _Float16 half8  __attribute__((ext_vector_type(8)));
typedef _Float16 half4v __attribute__((ext_vector_type(4)));
typedef float    floatx16 __attribute__((ext_vector_type(16)));

typedef __attribute__((address_space(3))) unsigned char lds_u8_t;
typedef __attribute__((address_space(1))) unsigned char gbl_u8_t;

// async global->LDS, 16B/lane; HW writes lane i at ldsbase + i*16 (wave-uniform base)
__device__ __forceinline__ void g2l16(const void* g, void* l) {
  __builtin_amdgcn_global_load_lds((const gbl_u8_t*)g, (lds_u8_t*)l, 16, 0, 0);
}

// ---------------- fused prep: gates + cast + 2 transposes in ONE dispatch ---
#define GATES_NB 256
#define CAST_NB  4096
#define DT_NB    2048
#define UT_NB    2048
#define PREP_NB  (GATES_NB + CAST_NB + DT_NB + UT_NB)

__global__ __launch_bounds__(256)
void prep_kernel(const float* __restrict__ enr, const float* __restrict__ cw,
                 const float* __restrict__ cb, const float* __restrict__ inter,
                 const float* __restrict__ dproj, const float* __restrict__ uproj,
                 float* __restrict__ gates, _Float16* __restrict__ Xh,
                 _Float16* __restrict__ BT1, _Float16* __restrict__ UT) {
  __shared__ __align__(16) char smem_raw[25664];
  const int tid = threadIdx.x;
  int bx = blockIdx.x;

  if (bx < GATES_NB) {   // ---- gates: conv(k=5, 64ch mix) + sigmoid ----
    float (*sw)[321] = (float (*)[321])smem_raw;            // 16*321*4 = 20544 B
    float (*se)[NIN] = (float (*)[NIN])(smem_raw + 20544);  // 20*64*4  =  5120 B
    const int t0 = bx * 16;
    const int b = t0 / S_DIM, s0 = t0 % S_DIM;   // 16 | S: no b-straddle
    for (int i = tid; i < NP * 320; i += 256) sw[i / 320][i % 320] = cw[i];
    for (int i = tid; i < 20 * NIN; i += 256) {
      int r = i >> 6, c = i & 63, s = s0 + r - 2;
      se[r][c] = (s >= 0 && s < S_DIM) ? enr[((size_t)b * S_DIM + s) * NIN + c] : 0.f;
    }
    __syncthreads();
    const int lt = tid >> 4, n = tid & 15;
    float acc = cb[n];
    #pragma unroll
    for (int dh = 0; dh < 5; ++dh) {
      const float* wrow = &sw[n][dh * 64];
      const float* erow = se[lt + dh];
      #pragma unroll
      for (int j = 0; j < NIN; ++j) acc += erow[j] * wrow[j];
    }
    gates[(size_t)(t0 + lt) * NP + n] = 1.f / (1.f + expf(-acc));
    return;
  }
  bx -= GATES_NB;
  if (bx < CAST_NB) {    // ---- X fp32 -> fp16, float4 vectorized ----
    int i = bx * 256 + tid;
    float4 v = reinterpret_cast<const float4*>(inter)[i];
    half4v o;
    o[0] = (_Float16)v.x; o[1] = (_Float16)v.y; o[2] = (_Float16)v.z; o[3] = (_Float16)v.w;
    reinterpret_cast<half4v*>(Xh)[i] = o;
    return;
  }
  bx -= CAST_NB;
  // ---- tiled transpose+cast ----
  const float* src; _Float16* dst; int rows, cols, bxt, byt;
  if (bx < DT_NB) {      // dproj[n]: (1024x128) -> BT1 block n (128x1024)
    int n = bx >> 7, rem = bx & 127;
    src = dproj + (size_t)n * H_DIM * R_DIM;
    dst = BT1 + (size_t)n * R_DIM * H_DIM;
    rows = H_DIM; cols = R_DIM; bxt = rem & 3; byt = rem >> 2;
  } else {               // uproj: (2048x1024) -> UT (1024x2048)
    bx -= DT_NB;
    src = uproj; dst = UT; rows = N1; cols = H_DIM;
    bxt = bx & 31; byt = bx >> 5;
  }
  float (*tile)[33] = (float (*)[33])smem_raw;
  const int c0 = bxt * 32, r0 = byt * 32;
  const int tx = tid & 31, ty = tid >> 5;   // 32 x 8
  #pragma unroll
  for (int k = 0; k < 32; k += 8)
    tile[ty + k][tx] = src[(size_t)(r0 + ty + k) * cols + c0 + tx];
  __syncthreads();
  #pragma unroll
  for (int k = 0; k < 32; k += 8)
    dst[(size_t)(c0 + ty + k) * rows + r0 + tx] = (_Float16)tile[tx][ty + k];
}

// ---------------- MFMA GEMM: C(MxN) = A(MxK) * BT(NxK)^T --------------------
// BM x BN tile, BK=128 (256B LDS rows = 16 x 16B chunks), 2x2 waves,
// 32x32x16 f16 MFMA, 2x2 register blocking (GEMM1) / 1x2 (GEMM2).
// XOR swizzle: physical chunk position p = logical_chunk ^ (row & 15); the
// staging lane fetches logical chunk ql^(row&15) so the DMA's lane-order
// write places it at position ql. Read: p = (2h+kh) ^ (r&15) -> 8 lanes per
// 4-bank group, balanced (8-cycle floor per b128).
template <int BM, int BN, int GATE>
__global__ __launch_bounds__(256)
void gemm_bt(const _Float16* __restrict__ A, const _Float16* __restrict__ BT,
             const float* __restrict__ gates, void* __restrict__ Cv,
             const int N, const int K) {
  constexpr int BK = 128, NCH = BK / 8;       // 16 chunks of 16B per row
  constexpr int RPC = 64 / NCH;               // 4 rows per 1KB staging call
  constexpr int WM = BM / 2, WN = BN / 2;
  constexpr int MI = WM / 32, NJ = WN / 32;
  constexpr int CA = BM * BK / 2048, CB = BN * BK / 2048;  // calls/wave
  __shared__ _Float16 sA[BM * BK];
  __shared__ _Float16 sB[BN * BK];
  __shared__ float sg[BM];

  const int tid = threadIdx.x, wave = tid >> 6, lane = tid & 63;
  const int m0 = blockIdx.y * BM, n0 = blockIdx.x * BN;
  const int wr = (wave >> 1) * WM, wc = (wave & 1) * WN;
  const int rl = lane >> 4;            // staging: row within 4-row call
  const int ql = lane & 15;            // staging: physical chunk position
  const int r = lane & 31, kh = lane >> 5;

  if (GATE && tid < BM) sg[tid] = gates[(size_t)(m0 + tid) * NP + blockIdx.x];

  floatx16 acc[MI][NJ];
  #pragma unroll
  for (int i = 0; i < MI; ++i)
    #pragma unroll
    for (int j = 0; j < NJ; ++j) acc[i][j] = (floatx16)0.f;

  for (int k0 = 0; k0 < K; k0 += BK) {
    __syncthreads();
    #pragma unroll
    for (int c = 0; c < CA; ++c) {
      const int rowL = wave * CA * RPC + c * RPC + rl;
      const int q = ql ^ (rowL & (NCH - 1));
      g2l16(A + (size_t)(m0 + rowL) * K + k0 + q * 8, sA + (size_t)rowL * BK);
    }
    #pragma unroll
    for (int c = 0; c < CB; ++c) {
      const int rowL = wave * CB * RPC + c * RPC + rl;
      const int q = ql ^ (rowL & (NCH - 1));
      g2l16(BT + (size_t)(n0 + rowL) * K + k0 + q * 8, sB + (size_t)rowL * BK);
    }
    __syncthreads();
    #pragma unroll
    for (int h = 0; h < BK / 16; ++h) {
      const int p8 = (((2 * h + kh) ^ (r & 15))) * 8;  // swizzled 16B slot
      half8 af[MI], bf[NJ];
      #pragma unroll
      for (int i = 0; i < MI; ++i)
        af[i] = *reinterpret_cast<const half8*>(&sA[(wr + i * 32 + r) * BK + p8]);
      #pragma unroll
      for (int j = 0; j < NJ; ++j)
        bf[j] = *reinterpret_cast<const half8*>(&sB[(wc + j * 32 + r) * BK + p8]);
      #pragma unroll
      for (int i = 0; i < MI; ++i)
        #pragma unroll
        for (int j = 0; j < NJ; ++j)
          acc[i][j] = __builtin_amdgcn_mfma_f32_32x32x16_f16(af[i], bf[j], acc[i][j], 0, 0, 0);
    }
  }

  // 32x32 C/D layout: col = lane&31, row = (reg&3) + 8*(reg>>2) + 4*kh
  if (GATE) {
    _Float16* C = (_Float16*)Cv;   // BN==128 -> blockIdx.x == neuron n
    #pragma unroll
    for (int i = 0; i < MI; ++i)
      #pragma unroll
      for (int g4 = 0; g4 < 4; ++g4)
        #pragma unroll
        for (int rr = 0; rr < 4; ++rr) {
          const int rowL = wr + i * 32 + rr + 8 * g4 + 4 * kh;
          const float g = sg[rowL];
          #pragma unroll
          for (int j = 0; j < NJ; ++j)
            C[(size_t)(m0 + rowL) * N + n0 + wc + j * 32 + r] =
                (_Float16)(acc[i][j][g4 * 4 + rr] * g);
        }
  } else {
    float* C = (float*)Cv;
    #pragma unroll
    for (int i = 0; i < MI; ++i)
      #pragma unroll
      for (int g4 = 0; g4 < 4; ++g4)
        #pragma unroll
        for (int rr = 0; rr < 4; ++rr) {
          const int rowL = wr + i * 32 + rr + 8 * g4 + 4 * kh;
          #pragma unroll
          for (int j = 0; j < NJ; ++j)
            C[(size_t)(m0 + rowL) * N + n0 + wc + j * 32 + r] = acc[i][j][g4 * 4 + rr];
        }
  }
}

extern "C" void kernel_launch(void* const* d_in, const int* in_sizes, int n_in,
                              void* d_out, int out_size, void* d_ws, size_t ws_size,
                              hipStream_t stream) {
  const float* inter = (const float*)d_in[0];  // (B,S,H)
  const float* enr   = (const float*)d_in[1];  // (B,S,64)
  const float* convw = (const float*)d_in[2];  // (16,1,5,64)
  const float* convb = (const float*)d_in[3];  // (16,)
  const float* dproj = (const float*)d_in[4];  // (16,1024,128)
  const float* uproj = (const float*)d_in[5];  // (16,128,1024)
  float* out   = (float*)d_out;                // (B,S,H) fp32
  float* gates = out + (size_t)T_TOK * H_DIM;  // (B,S,16) fp32 = output 1

  // workspace: Xh(8MB) | BT1(4MB) | UT(4MB) | Dsc(16MB)
  _Float16* Xh  = (_Float16*)d_ws;
  _Float16* BT1 = Xh  + (size_t)T_TOK * H_DIM;
  _Float16* UT  = BT1 + (size_t)N1 * H_DIM;
  _Float16* Dsc = UT  + (size_t)H_DIM * N1;

  // 1. all prep in one dispatch
  prep_kernel<<<PREP_NB, 256, 0, stream>>>(enr, convw, convb, inter, dproj, uproj,
                                           gates, Xh, BT1, UT);
  // 2. Dsc[t, n*128+r] = gate[t,n] * sum_h X[t,h] * dproj[n,h,r]
  gemm_bt<128, 128, 1><<<dim3(N1 / 128, T_TOK / 128), 256, 0, stream>>>(
      Xh, BT1, gates, (void*)Dsc, N1, H_DIM);
  // 3. out[t,h] = sum_nr Dsc[t,nr] * uproj[nr,h]   (64x128 tile -> 512 blocks)
  gemm_bt<64, 128, 0><<<dim3(H_DIM / 128, T_TOK / 64), 256, 0, stream>>>(
      Dsc, UT, nullptr, (void*)out, H_DIM, N1);
}